// Round 12
// baseline (110.049 us; speedup 1.0000x reference)
//
#include <hip/hip_runtime.h>
#include <math.h>

#define NN 10000
#define EE 640000
#define DD 256
#define NBK 250             // src buckets == conv blocks (full chip), NPB exact
#define NPB 40              // nodes per bucket: 250*40 = 10000 exactly
#define NWRT 256            // sorter blocks
#define EPW (EE / NWRT)     // 2500 edges per sorter
#define MAXB 3072           // slots per bucket (mean 2560, +10 sigma)
#define NDEG 64             // deg-scatter blocks in K1
#define EPD (EE / NDEG)     // 10000
#define NTHR 512

// ws float offsets (~28.9 MB)
#define OFF_DINV 0
#define OFF_XW   (NN)
#define OFF_C1   (2*NN)
#define OFF_C2   (3*NN)
#define OFF_XP   (4*NN)               // [0..143] xp1, [144] regAcc, int ctr at [152]
#define OFF_GCUR (4*NN + 160)         // int[256] global bucket cursors (memset 0)
#define OFF_S1   (4*NN + 416)         // uint2[NBK*MAXB] compact bucket spans
#define OFF_DEGP (OFF_S1 + 2*NBK*MAXB)   // float[NDEG][NN]
#define OFF_PA   (OFF_DEGP + NDEG*NN)    // float[NBK][NN]
#define OFF_PB   (OFF_PA + NBK*NN)       // float[NBK][NN]

// K1: blocks 0..255: two-pass LDS counting-sort of 2500 edges into EXACT
//     per-bucket global runs (reserved via gcur atomics); blocks 0..249 also
//     compute xw = x@W1 (40 rows each). Blocks 256..319: LDS deg-scatter.
__global__ __launch_bounds__(NTHR) void k1_sort_deg_xw(
    const int* __restrict__ src, const int* __restrict__ dst,
    const float* __restrict__ ew, const float* __restrict__ x,
    const float* __restrict__ W1, float* __restrict__ ws)
{
    __shared__ unsigned raw[11392];       // 45568 B union
    int tid = threadIdx.x, bid = blockIdx.x;
    int lane = tid & 63, wv = tid >> 6;
    if (bid < NWRT) {
        unsigned* s_key  = raw;                    // [0,2500)
        float*    s_val  = (float*)(raw + EPW);    // [2500,5000)
        unsigned* s_okey = raw + 2 * EPW;          // [5000,7500)
        float*    s_oval = (float*)(raw + 3 * EPW);// [7500,10000)
        int* s_cnt   = (int*)(raw + 10000);        // 256
        int* s_sincl = (int*)(raw + 10256);        // 256
        int* s_baseL = (int*)(raw + 10512);        // 256
        int* s_lcur  = (int*)(raw + 10768);        // 256
        int* s_posg  = (int*)(raw + 11024);        // 256
        int* s_wtot  = (int*)(raw + 11280);        // 4
        if (bid == 0 && tid < 160) ws[OFF_XP + tid] = 0.f;   // xp1+reg+done-ctr
        if (tid < 256) s_cnt[tid] = 0;
        __syncthreads();
        int base = bid * EPW;
        for (int k = tid; k < EPW; k += NTHR) {
            int s = src[base + k], d = dst[base + k];
            int j = s / NPB, loc = s - j * NPB;
            s_key[k] = (unsigned)d | ((unsigned)loc << 14) | ((unsigned)j << 20);
            s_val[k] = ew[base + k];
            atomicAdd(&s_cnt[j], 1);
        }
        __syncthreads();
        if (tid < 256) {                           // two-level exclusive scan
            int v = s_cnt[tid];
            int incl = v;
            #pragma unroll
            for (int off = 1; off < 64; off <<= 1) {
                int t = __shfl_up(incl, off);
                if (lane >= off) incl += t;
            }
            s_sincl[tid] = incl;
            if (lane == 63) s_wtot[tid >> 6] = incl;
        }
        __syncthreads();
        int* gcur = (int*)(ws + OFF_GCUR);
        if (tid < 256) {
            int w = tid >> 6, pre = 0;
            for (int q = 0; q < w; ++q) pre += s_wtot[q];
            int b = pre + s_sincl[tid] - s_cnt[tid];
            s_baseL[tid] = b;
            s_lcur[tid] = b;
            if (tid < NBK) s_posg[tid] = atomicAdd(&gcur[tid], s_cnt[tid]);
        }
        __syncthreads();
        for (int k = tid; k < EPW; k += NTHR) {    // bucket-order into okey/oval
            unsigned ky = s_key[k];
            int j = ky >> 20;
            int r = atomicAdd(&s_lcur[j], 1);
            s_okey[r] = ky & 0xFFFFFu;
            s_oval[r] = s_val[k];
        }
        __syncthreads();
        uint2* S1 = (uint2*)(ws + OFF_S1);
        for (int j = wv; j < NBK; j += 8) {        // coalesced per-bucket runs
            int c = s_cnt[j], bl = s_baseL[j];
            size_t gb = (size_t)j * MAXB + s_posg[j];
            for (int k = lane; k < c; k += 64)
                S1[gb + k] = make_uint2(s_okey[bl + k], __float_as_uint(s_oval[bl + k]));
        }
        if (bid < NBK) {                           // xw for own 40 rows
            float4 wreg = reinterpret_cast<const float4*>(W1)[lane];
            #pragma unroll
            for (int rr = 0; rr < 5; ++rr) {
                int row = bid * NPB + wv * 5 + rr;
                float4 a = reinterpret_cast<const float4*>(x + (size_t)row * DD)[lane];
                float v = a.x*wreg.x + a.y*wreg.y + a.z*wreg.z + a.w*wreg.w;
                #pragma unroll
                for (int off = 32; off; off >>= 1) v += __shfl_xor(v, off);
                if (lane == 0) ws[OFF_XW + row] = v;
            }
        }
    } else {
        float* acc = (float*)raw;                  // 40 KB deg accumulator
        for (int i = tid; i < NN; i += NTHR) acc[i] = 0.f;
        __syncthreads();
        int base = (bid - NWRT) * EPD;
        for (int k = tid; k < EPD; k += NTHR)
            atomicAdd(&acc[dst[base + k]], ew[base + k]);
        __syncthreads();
        float* dp = ws + OFF_DEGP + (size_t)(bid - NWRT) * NN;
        for (int i = tid; i < NN; i += NTHR) dp[i] = acc[i];
    }
}

// scatter own compact span into LDS acc; flush to pout slice bid.
#define SCATTER_SPAN(POUT)                                                   \
    {                                                                        \
        const uint2* span = (const uint2*)(ws + OFF_S1) + (size_t)bid * MAXB;\
        int glen = ((const int*)(ws + OFF_GCUR))[bid];                       \
        for (int k = tid; k < glen; k += NTHR) {                             \
            uint2 pk = span[k];                                              \
            atomicAdd(&acc[pk.x & 0x3FFF],                                   \
                      __uint_as_float(pk.y) * du[pk.x >> 14]);               \
        }                                                                    \
        __syncthreads();                                                     \
        float* pp = (POUT) + (size_t)bid * NN;                               \
        for (int i = tid; i < NN; i += NTHR) pp[i] = acc[i];                 \
    }

// K2: finalize deg (64 slices) -> dinv, du0 = dinv*xw; scatter conv1 -> PA.
__global__ __launch_bounds__(NTHR) void k2_dinv_scat1(float* __restrict__ ws)
{
    __shared__ float acc[NN];
    __shared__ float red[8][NPB];
    __shared__ float du[NPB];
    int tid = threadIdx.x, bid = blockIdx.x;
    int lane = tid & 63, wv = tid >> 6;
    int nbase = bid * NPB;
    const float* dp = ws + OFF_DEGP;
    if (lane < NPB) {
        float s = 0.f;
        #pragma unroll
        for (int q = 0; q < 8; ++q)
            s += dp[(size_t)(wv * 8 + q) * NN + nbase + lane];
        red[wv][lane] = s;
    }
    __syncthreads();
    if (tid < NPB) {
        float tot = 1.f;                     // self-loop weight
        #pragma unroll
        for (int q = 0; q < 8; ++q) tot += red[q][tid];
        float di = (tot > 0.f) ? 1.0f / sqrtf(tot) : 0.f;
        ws[OFF_DINV + nbase + tid] = di;
        du[tid] = di * ws[OFF_XW + nbase + tid];
    }
    for (int i = tid; i < NN; i += NTHR) acc[i] = 0.f;
    __syncthreads();
    SCATTER_SPAN(ws + OFF_PA)
}

// K3/K4: finalize conv from 250 slices (c = M*di*(sum + di*hin) + B), du=di*c;
//        scatter next layer.
__global__ __launch_bounds__(NTHR) void k_conv(
    const float* __restrict__ hin, const float* __restrict__ multp,
    const float* __restrict__ biasp, float* __restrict__ cout,
    const float* __restrict__ pin, float* __restrict__ pout,
    float* __restrict__ ws)
{
    __shared__ float acc[NN];
    __shared__ float red[8][NPB];
    __shared__ float du[NPB];
    int tid = threadIdx.x, bid = blockIdx.x;
    int lane = tid & 63, wv = tid >> 6;
    int nbase = bid * NPB;
    if (lane < NPB) {
        float s = 0.f;
        for (int qq = 0; qq < 32; ++qq) {
            int sl = wv * 32 + qq;
            if (sl < NBK) s += pin[(size_t)sl * NN + nbase + lane];
        }
        red[wv][lane] = s;
    }
    __syncthreads();
    if (tid < NPB) {
        float tot = 0.f;
        #pragma unroll
        for (int q = 0; q < 8; ++q) tot += red[q][tid];
        float di = ws[OFF_DINV + nbase + tid];
        float M = multp ? *multp : 1.0f;
        float cv = M * di * (tot + di * hin[nbase + tid]) + *biasp;
        cout[nbase + tid] = cv;
        du[tid] = di * cv;
    }
    for (int i = tid; i < NN; i += NTHR) acc[i] = 0.f;
    __syncthreads();
    SCATTER_SPAN(pout)
}

// K5: finalize conv3 (local sc3); pool stage 1 over own 40 rows; last-done
//     block runs pool stages 2..4 and writes out.
__global__ __launch_bounds__(NTHR) void k5_final(
    const float* __restrict__ multp, const float* __restrict__ biasp,
    const float* __restrict__ pin,
    const float* __restrict__ P1, const float* __restrict__ P2,
    const float* __restrict__ P3, float* __restrict__ ws, float* __restrict__ out)
{
    __shared__ float red[8][NPB];
    __shared__ float sc3[NPB];
    __shared__ float part[8][48][3];
    __shared__ float entW[8];
    __shared__ int sh_last;
    int tid = threadIdx.x, bid = blockIdx.x;
    int lane = tid & 63, wv = tid >> 6;
    int nbase = bid * NPB;
    const float* c1 = ws + OFF_C1;
    const float* c2 = ws + OFF_C2;
    if (lane < NPB) {
        float s = 0.f;
        for (int qq = 0; qq < 32; ++qq) {
            int sl = wv * 32 + qq;
            if (sl < NBK) s += pin[(size_t)sl * NN + nbase + lane];
        }
        red[wv][lane] = s;
    }
    __syncthreads();
    if (tid < NPB) {
        float tot = 0.f;
        #pragma unroll
        for (int q = 0; q < 8; ++q) tot += red[q][tid];
        float di = ws[OFF_DINV + nbase + tid];
        sc3[tid] = (*multp) * di * (tot + di * c2[nbase + tid]) + *biasp;
    }
    __syncthreads();
    float a0 = 0.f, a1 = 0.f, a2 = 0.f, ent = 0.f;
    #pragma unroll
    for (int r = 0; r < 5; ++r) {
        int l = wv * 5 + r;
        int row = nbase + l;
        float pv = (lane < 48) ? P1[(size_t)row * 48 + lane] : -1e30f;
        float mx = pv;
        #pragma unroll
        for (int off = 32; off; off >>= 1) mx = fmaxf(mx, __shfl_xor(mx, off));
        float e = (lane < 48) ? expf(pv - mx) : 0.f;
        float sum = e;
        #pragma unroll
        for (int off = 32; off; off >>= 1) sum += __shfl_xor(sum, off);
        float p = e / sum;
        if (lane < 48) {
            ent -= p * logf(p + 1e-12f);
            a0 += p * c1[row];
            a1 += p * c2[row];
            a2 += p * sc3[l];
        }
    }
    #pragma unroll
    for (int off = 32; off; off >>= 1) ent += __shfl_xor(ent, off);
    if (lane == 0) entW[wv] = ent;
    if (lane < 48) { part[wv][lane][0] = a0; part[wv][lane][1] = a1; part[wv][lane][2] = a2; }
    __syncthreads();
    float* xp1 = ws + OFF_XP;
    if (tid < 144) {
        int j = tid / 3, col = tid % 3;
        float sp = 0.f;
        #pragma unroll
        for (int w = 0; w < 8; ++w) sp += part[w][j][col];
        atomicAdd(&xp1[j * 3 + col], sp);
    }
    if (tid == 0) {
        float sp = 0.f;
        #pragma unroll
        for (int w = 0; w < 8; ++w) sp += entW[w];
        atomicAdd(&xp1[144], sp);
    }
    if (tid == 0) {
        __threadfence();
        int old = atomicAdd((int*)ws + OFF_XP + 152, 1);
        sh_last = (old == (int)gridDim.x - 1) ? 1 : 0;
    }
    __syncthreads();
    if (sh_last) {
        __shared__ float shXp[145];
        __shared__ float S2[48][12], xp2[12][3];
        __shared__ float S3[12][4], xp3[4][3];
        __shared__ float ent2, ent3;
        if (tid < 145) shXp[tid] = atomicAdd(&xp1[tid], 0.0f);   // coherent read
        if (tid == 0) { ent2 = 0.f; ent3 = 0.f; }
        __syncthreads();
        if (tid < 48) {
            float v[12], mx = -1e30f;
            #pragma unroll
            for (int j = 0; j < 12; j++) { v[j] = P2[tid * 12 + j]; mx = fmaxf(mx, v[j]); }
            float sm = 0.f;
            #pragma unroll
            for (int j = 0; j < 12; j++) { v[j] = expf(v[j] - mx); sm += v[j]; }
            float e = 0.f;
            #pragma unroll
            for (int j = 0; j < 12; j++) {
                float p = v[j] / sm; S2[tid][j] = p; e -= p * logf(p + 1e-12f);
            }
            atomicAdd(&ent2, e);
        }
        __syncthreads();
        if (tid < 36) {
            int j = tid / 3, col = tid % 3;
            float sm = 0.f;
            for (int i = 0; i < 48; i++) sm += S2[i][j] * shXp[i * 3 + col];
            xp2[j][col] = sm;
        }
        __syncthreads();
        if (tid < 12) {
            float v[4], mx = -1e30f;
            #pragma unroll
            for (int j = 0; j < 4; j++) { v[j] = P3[tid * 4 + j]; mx = fmaxf(mx, v[j]); }
            float sm = 0.f;
            #pragma unroll
            for (int j = 0; j < 4; j++) { v[j] = expf(v[j] - mx); sm += v[j]; }
            float e = 0.f;
            #pragma unroll
            for (int j = 0; j < 4; j++) {
                float p = v[j] / sm; S3[tid][j] = p; e -= p * logf(p + 1e-12f);
            }
            atomicAdd(&ent3, e);
        }
        __syncthreads();
        if (tid < 12) {
            int j = tid / 3, col = tid % 3;
            float sm = 0.f;
            for (int i = 0; i < 12; i++) sm += S3[i][j] * xp2[i][col];
            xp3[j][col] = sm;
        }
        __syncthreads();
        if (tid == 0) {
            float o0 = 0.f, o1 = 0.f, o2 = 0.f;
            for (int i = 0; i < 4; i++) {
                o0 += xp3[i][0]; o1 += xp3[i][1]; o2 += xp3[i][2];
            }
            // stage-4: width-1 softmax -> p==1, entropy==0 in fp32
            float reg = shXp[144] / (float)NN + ent2 / 48.f + ent3 / 12.f;
            out[0] = o0; out[1] = o1; out[2] = o2; out[3] = reg;
        }
    }
}

extern "C" void kernel_launch(void* const* d_in, const int* in_sizes, int n_in,
                              void* d_out, int out_size, void* d_ws, size_t ws_size,
                              hipStream_t stream) {
    const float* x  = (const float*)d_in[0];
    const int*   ei = (const int*)d_in[1];
    const float* ea = (const float*)d_in[2];
    // d_in[3] = adj — unused by the reference.
    const float* W1 = (const float*)d_in[4];
    const float* b1 = (const float*)d_in[5];
    const float* W2 = (const float*)d_in[6];
    const float* b2 = (const float*)d_in[7];
    const float* P1 = (const float*)d_in[8];
    const float* P2 = (const float*)d_in[9];
    const float* P3 = (const float*)d_in[10];
    // d_in[11] = P4 — width-1 softmax, handled analytically.
    const int* src = ei;
    const int* dst = ei + EE;
    float* ws  = (float*)d_ws;
    float* out = (float*)d_out;

    float* xw    = ws + OFF_XW;
    float* c1    = ws + OFF_C1;
    float* c2    = ws + OFF_C2;
    float* partA = ws + OFF_PA;
    float* partB = ws + OFF_PB;

    hipMemsetAsync(ws + OFF_GCUR, 0, 256 * sizeof(int), stream);
    k1_sort_deg_xw<<<NWRT + NDEG, NTHR, 0, stream>>>(src, dst, ea, x, W1, ws);
    k2_dinv_scat1<<<NBK, NTHR, 0, stream>>>(ws);
    k_conv<<<NBK, NTHR, 0, stream>>>(xw, nullptr, b1, c1, partA, partB, ws);
    k_conv<<<NBK, NTHR, 0, stream>>>(c1, W2, b2, c2, partB, partA, ws);
    k5_final<<<NBK, NTHR, 0, stream>>>(W2, b2, partA, P1, P2, P3, ws, out);
}

// Round 13
// 80.886 us; speedup vs baseline: 1.3605x; 1.3605x over previous
//
#include <hip/hip_runtime.h>
#include <math.h>

#define NN 10000
#define EE 640000
#define DD 256
#define SB 128            // scatter blocks per edge pass; EE/SB = 5000 edges each
#define EPB (EE / SB)
#define NTHR 512
#define RB 157            // reduce blocks: 157*64 = 10048 >= NN

// ws float-offset layout
#define OFF_DINV 0
#define OFF_XW   (NN)
#define OFF_C1   (2*NN)
#define OFF_C2   (3*NN)
#define OFF_U0   (4*NN)
#define OFF_U1   (5*NN)
#define OFF_U2   (6*NN)
#define OFF_XP   (7*NN)         // [0..143] xp1, [144] regAcc, int done-ctr at [152]
#define OFF_PART (7*NN + 160)   // SB*NN floats (5.12 MB), reused each pass

// K1: deg scatter (blocks 0..SB-1: LDS acc, coalesced flush to partials)
//     + xw = x@W1 fused (all 256 blocks, wave per row).
__global__ __launch_bounds__(NTHR) void k1_deg_xw(
    const int* __restrict__ dst, const float* __restrict__ ew,
    const float* __restrict__ x, const float* __restrict__ W1,
    float* __restrict__ ws)
{
    __shared__ float acc[NN];    // 40 KB
    int tid = threadIdx.x, bid = blockIdx.x;
    int lane = tid & 63, wv = tid >> 6;
    if (bid == 0 && tid < 160) ws[OFF_XP + tid] = 0.f;   // xp1 + reg + done-ctr
    if (bid < SB) {
        for (int i = tid; i < NN; i += NTHR) acc[i] = 0.f;
    }
    __syncthreads();
    {   // xw: wave per row, float4 dot + butterfly (256 blocks x 8 waves)
        float4 wreg = reinterpret_cast<const float4*>(W1)[lane];
        float* xw = ws + OFF_XW;
        for (int row = bid * 8 + wv; row < NN; row += 256 * 8) {
            float4 a = reinterpret_cast<const float4*>(x + (size_t)row * DD)[lane];
            float v = a.x*wreg.x + a.y*wreg.y + a.z*wreg.z + a.w*wreg.w;
            #pragma unroll
            for (int off = 32; off; off >>= 1) v += __shfl_xor(v, off);
            if (lane == 0) xw[row] = v;
        }
    }
    if (bid < SB) {
        int base = bid * EPB;
        for (int k = tid; k < EPB; k += NTHR) {
            int e = base + k;
            atomicAdd(&acc[dst[e]], ew[e]);
        }
        __syncthreads();
        float* p = ws + OFF_PART + (size_t)bid * NN;
        for (int i = tid; i < NN; i += NTHR) p[i] = acc[i];
    }
}

// K2: reduce deg partials -> dinv = (1+deg)^(-1/2); u0 = dinv*xw.
// Block: 64 nodes x 8 waves of SB/8=16 slices; all loads wave-coalesced.
__global__ __launch_bounds__(NTHR) void k2_dinv(float* __restrict__ ws)
{
    __shared__ float red[8][64];
    int tid = threadIdx.x, bid = blockIdx.x;
    int nl = tid & 63, sl = tid >> 6;
    int node = bid * 64 + nl;
    const float* part = ws + OFF_PART;
    float s = 0.f;
    if (node < NN) {
        #pragma unroll 8
        for (int it = 0; it < SB / 8; ++it)
            s += part[(size_t)(sl * (SB / 8) + it) * NN + node];
    }
    red[sl][nl] = s;
    __syncthreads();
    if (tid < 64 && node < NN) {
        float tot = 1.f;                   // self-loop weight
        #pragma unroll
        for (int q = 0; q < 8; ++q) tot += red[q][tid];
        float di = (tot > 0.f) ? 1.0f / sqrtf(tot) : 0.f;
        ws[OFF_DINV + node] = di;
        ws[OFF_U0 + node] = di * ws[OFF_XW + node];
    }
}

// K3/K5/K7: edge scatter of ew[e]*u[src[e]] into LDS by dst, coalesced flush.
__global__ __launch_bounds__(NTHR) void k_scat(
    const int* __restrict__ src, const int* __restrict__ dst,
    const float* __restrict__ ew, const float* __restrict__ u,
    float* __restrict__ ws)
{
    __shared__ float acc[NN];
    int tid = threadIdx.x, bid = blockIdx.x;
    for (int i = tid; i < NN; i += NTHR) acc[i] = 0.f;
    __syncthreads();
    int base = bid * EPB;
    for (int k = tid; k < EPB; k += NTHR) {
        int e = base + k;
        atomicAdd(&acc[dst[e]], ew[e] * u[src[e]]);
    }
    __syncthreads();
    float* p = ws + OFF_PART + (size_t)bid * NN;
    for (int i = tid; i < NN; i += NTHR) p[i] = acc[i];
}

// K4/K6: reduce conv partials: c = M*di*(sum + di*hin) + B ; u = di*c.
__global__ __launch_bounds__(NTHR) void k_red_conv(
    const float* __restrict__ hin, const float* __restrict__ multp,
    const float* __restrict__ biasp, float* __restrict__ cout,
    float* __restrict__ uout, float* __restrict__ ws)
{
    __shared__ float red[8][64];
    int tid = threadIdx.x, bid = blockIdx.x;
    int nl = tid & 63, sl = tid >> 6;
    int node = bid * 64 + nl;
    const float* part = ws + OFF_PART;
    float s = 0.f;
    if (node < NN) {
        #pragma unroll 8
        for (int it = 0; it < SB / 8; ++it)
            s += part[(size_t)(sl * (SB / 8) + it) * NN + node];
    }
    red[sl][nl] = s;
    __syncthreads();
    if (tid < 64 && node < NN) {
        float tot = 0.f;
        #pragma unroll
        for (int q = 0; q < 8; ++q) tot += red[q][tid];
        float di = ws[OFF_DINV + node];
        float M = multp ? *multp : 1.0f;
        float cv = M * di * (tot + di * hin[node]) + *biasp;
        cout[node] = cv;
        uout[node] = di * cv;
    }
}

// K8: reduce -> c3 (block-local), pool stage 1 for the block's 64 rows,
//     last-done block runs pool stages 2..4 and writes out.
__global__ __launch_bounds__(NTHR) void k8_final(
    const float* __restrict__ hin,                         // c2
    const float* __restrict__ multp, const float* __restrict__ biasp,
    const float* __restrict__ c1, const float* __restrict__ c2,
    const float* __restrict__ P1, const float* __restrict__ P2,
    const float* __restrict__ P3, float* __restrict__ ws, float* __restrict__ out)
{
    __shared__ float red[8][64];
    __shared__ float s_c3[64];
    __shared__ float part[8][48][3];
    __shared__ float entW[8];
    __shared__ int sh_last;
    int tid = threadIdx.x, bid = blockIdx.x;
    int lane = tid & 63, wv = tid >> 6;
    int node = bid * 64 + lane;
    const float* partg = ws + OFF_PART;
    float s = 0.f;
    if (node < NN) {
        #pragma unroll 8
        for (int it = 0; it < SB / 8; ++it)
            s += partg[(size_t)(wv * (SB / 8) + it) * NN + node];
    }
    red[wv][lane] = s;
    __syncthreads();
    if (tid < 64) {
        float cv = 0.f;
        if (node < NN) {
            float tot = 0.f;
            #pragma unroll
            for (int q = 0; q < 8; ++q) tot += red[q][tid];
            float di = ws[OFF_DINV + node];
            cv = (*multp) * di * (tot + di * hin[node]) + *biasp;
        }
        s_c3[tid] = cv;
    }
    __syncthreads();
    // ---- pool stage 1 over this block's rows: wave wv -> rows wv*8..wv*8+7 ----
    float a0 = 0.f, a1 = 0.f, a2 = 0.f, ent = 0.f;
    for (int j = 0; j < 8; ++j) {
        int rl = wv * 8 + j;
        int row = bid * 64 + rl;
        if (row >= NN) break;                        // wave-uniform
        float v = (lane < 48) ? P1[(size_t)row * 48 + lane] : -1e30f;
        float mx = v;
        #pragma unroll
        for (int off = 32; off; off >>= 1) mx = fmaxf(mx, __shfl_xor(mx, off));
        float e = (lane < 48) ? expf(v - mx) : 0.f;
        float sum = e;
        #pragma unroll
        for (int off = 32; off; off >>= 1) sum += __shfl_xor(sum, off);
        float p = e / sum;
        if (lane < 48) {
            ent -= p * logf(p + 1e-12f);
            a0 += p * c1[row];
            a1 += p * c2[row];
            a2 += p * s_c3[rl];
        }
    }
    #pragma unroll
    for (int off = 32; off; off >>= 1) ent += __shfl_xor(ent, off);
    if (lane == 0) entW[wv] = ent;
    if (lane < 48) { part[wv][lane][0] = a0; part[wv][lane][1] = a1; part[wv][lane][2] = a2; }
    __syncthreads();
    float* xp1 = ws + OFF_XP;
    if (tid < 144) {
        int j = tid / 3, col = tid % 3;
        float sp = 0.f;
        #pragma unroll
        for (int w = 0; w < 8; ++w) sp += part[w][j][col];
        atomicAdd(&xp1[j * 3 + col], sp);
    }
    if (tid == 0) {
        float sp = 0.f;
        #pragma unroll
        for (int w = 0; w < 8; ++w) sp += entW[w];
        atomicAdd(&xp1[144], sp);
    }
    // ---- last-block epilogue: pool stages 2..4 ----
    if (tid == 0) {
        __threadfence();
        int old = atomicAdd((int*)ws + OFF_XP + 152, 1);
        sh_last = (old == (int)gridDim.x - 1) ? 1 : 0;
    }
    __syncthreads();
    if (sh_last) {
        __shared__ float shXp[145];
        __shared__ float S2[48][12], xp2[12][3];
        __shared__ float S3[12][4], xp3[4][3];
        __shared__ float ent2, ent3;
        if (tid < 145) shXp[tid] = atomicAdd(&xp1[tid], 0.0f);  // coherent read
        if (tid == 0) { ent2 = 0.f; ent3 = 0.f; }
        __syncthreads();
        if (tid < 48) {
            float v[12], mx = -1e30f;
            #pragma unroll
            for (int j = 0; j < 12; j++) { v[j] = P2[tid * 12 + j]; mx = fmaxf(mx, v[j]); }
            float sm = 0.f;
            #pragma unroll
            for (int j = 0; j < 12; j++) { v[j] = expf(v[j] - mx); sm += v[j]; }
            float e = 0.f;
            #pragma unroll
            for (int j = 0; j < 12; j++) {
                float p = v[j] / sm; S2[tid][j] = p; e -= p * logf(p + 1e-12f);
            }
            atomicAdd(&ent2, e);
        }
        __syncthreads();
        if (tid < 36) {
            int j = tid / 3, col = tid % 3;
            float sm = 0.f;
            for (int i = 0; i < 48; i++) sm += S2[i][j] * shXp[i * 3 + col];
            xp2[j][col] = sm;
        }
        __syncthreads();
        if (tid < 12) {
            float v[4], mx = -1e30f;
            #pragma unroll
            for (int j = 0; j < 4; j++) { v[j] = P3[tid * 4 + j]; mx = fmaxf(mx, v[j]); }
            float sm = 0.f;
            #pragma unroll
            for (int j = 0; j < 4; j++) { v[j] = expf(v[j] - mx); sm += v[j]; }
            float e = 0.f;
            #pragma unroll
            for (int j = 0; j < 4; j++) {
                float p = v[j] / sm; S3[tid][j] = p; e -= p * logf(p + 1e-12f);
            }
            atomicAdd(&ent3, e);
        }
        __syncthreads();
        if (tid < 12) {
            int j = tid / 3, col = tid % 3;
            float sm = 0.f;
            for (int i = 0; i < 12; i++) sm += S3[i][j] * xp2[i][col];
            xp3[j][col] = sm;
        }
        __syncthreads();
        if (tid == 0) {
            float o0 = 0.f, o1 = 0.f, o2 = 0.f;
            for (int i = 0; i < 4; i++) {
                o0 += xp3[i][0]; o1 += xp3[i][1]; o2 += xp3[i][2];
            }
            // stage-4: width-1 softmax -> p==1, entropy==0 in fp32
            float reg = shXp[144] / (float)NN + ent2 / 48.f + ent3 / 12.f;
            out[0] = o0; out[1] = o1; out[2] = o2; out[3] = reg;
        }
    }
}

extern "C" void kernel_launch(void* const* d_in, const int* in_sizes, int n_in,
                              void* d_out, int out_size, void* d_ws, size_t ws_size,
                              hipStream_t stream) {
    const float* x  = (const float*)d_in[0];
    const int*   ei = (const int*)d_in[1];
    const float* ea = (const float*)d_in[2];
    // d_in[3] = adj — unused by the reference.
    const float* W1 = (const float*)d_in[4];
    const float* b1 = (const float*)d_in[5];
    const float* W2 = (const float*)d_in[6];
    const float* b2 = (const float*)d_in[7];
    const float* P1 = (const float*)d_in[8];
    const float* P2 = (const float*)d_in[9];
    const float* P3 = (const float*)d_in[10];
    // d_in[11] = P4 — width-1 softmax, handled analytically.
    const int* src = ei;
    const int* dst = ei + EE;
    float* ws  = (float*)d_ws;
    float* out = (float*)d_out;

    k1_deg_xw<<<256, NTHR, 0, stream>>>(dst, ea, x, W1, ws);
    k2_dinv<<<RB, NTHR, 0, stream>>>(ws);
    k_scat<<<SB, NTHR, 0, stream>>>(src, dst, ea, ws + OFF_U0, ws);
    k_red_conv<<<RB, NTHR, 0, stream>>>(ws + OFF_XW, nullptr, b1,
                                        ws + OFF_C1, ws + OFF_U1, ws);
    k_scat<<<SB, NTHR, 0, stream>>>(src, dst, ea, ws + OFF_U1, ws);
    k_red_conv<<<RB, NTHR, 0, stream>>>(ws + OFF_C1, W2, b2,
                                        ws + OFF_C2, ws + OFF_U2, ws);
    k_scat<<<SB, NTHR, 0, stream>>>(src, dst, ea, ws + OFF_U2, ws);
    k8_final<<<RB, NTHR, 0, stream>>>(ws + OFF_C2, W2, b2,
                                      ws + OFF_C1, ws + OFF_C2,
                                      P1, P2, P3, ws, out);
}